// Round 10
// baseline (149.197 us; speedup 1.0000x reference)
//
#include <hip/hip_runtime.h>
#include <cstdint>

typedef __attribute__((ext_vector_type(8))) short bf16x8;    // 8 bf16 = 4 VGPRs
typedef __attribute__((ext_vector_type(16))) float f32x16;   // 32x32 MFMA C/D
typedef __attribute__((ext_vector_type(4))) float f4;
typedef __attribute__((ext_vector_type(8))) unsigned short u16x8;
typedef unsigned short u16;

// JOURNAL:
// R6: __launch_bounds__(256,6) forced VGPR 72->40, scratch spills (+36MB traffic).
// R7: device-scope __threadfence() reduction inside gemm3 = L2 writeback storms,
//     ~140us penalty. Cross-block reduction stays a separate dispatch.
// R8: (256,8) neutral; residency saturated ~4 blocks/CU. Latency-hiding done.
// R9: 32x32x16 MFMA beats 16x16x32 (-5us): fewer insts, 8.07 vs 9.7 cyc/eqFLOP.
// R10: gemm3 256x64 tile (105 FLOP/staged-byte), KSPLIT=8, bf16 partials.

__device__ __forceinline__ u16 f2bf(float f) {
  uint32_t u = __builtin_bit_cast(uint32_t, f);
  u += 0x7fffu + ((u >> 16) & 1u);          // round-to-nearest-even
  return (u16)(u >> 16);
}

__device__ __forceinline__ float bf2f(u16 h) {
  return __builtin_bit_cast(float, (uint32_t)h << 16);
}

__device__ __forceinline__ void async_cp16(const void* g, void* l) {
  __builtin_amdgcn_global_load_lds(
      (const __attribute__((address_space(1))) uint32_t*)g,
      (__attribute__((address_space(3))) uint32_t*)l, 16, 0, 0);
}

// cast x | features | prototypes -> contiguous bf16 region in ws (8 elem/thread)
__global__ __launch_bounds__(256) void cast3(
    const float* __restrict__ x, const float* __restrict__ f,
    const float* __restrict__ p, u16* __restrict__ dst,
    int n1, int n2, int n3) {
  int i = (blockIdx.x * 256 + threadIdx.x) * 8;
  const float* src;
  int local;
  if (i < n1) { src = x; local = i; }
  else if (i < n1 + n2) { src = f; local = i - n1; }
  else if (i < n1 + n2 + n3) { src = p; local = i - n1 - n2; }
  else return;
  f4 a = *(const f4*)(src + local);
  f4 b = *(const f4*)(src + local + 4);
  u16x8 o;
  o[0] = f2bf(a.x); o[1] = f2bf(a.y); o[2] = f2bf(a.z); o[3] = f2bf(a.w);
  o[4] = f2bf(b.x); o[5] = f2bf(b.y); o[6] = f2bf(b.z); o[7] = f2bf(b.w);
  *(u16x8*)(dst + i) = o;
}

// ---- gemm12 main loop (TM=128, TN=64): C += A @ B^T with 32x32x16 MFMA ----
// A,B pre-offset to tile base row; 16B-chunk XOR swizzle (0 bank conflicts).
// Wave grid 2x2: wave covers 64 rows x 32 cols = 2 stacked 32x32 acc tiles.
__device__ __forceinline__ void mainloop(
    const u16* __restrict__ A, const u16* __restrict__ B, int K,
    int kbeg, int kend, int tid, u16* lds, f32x16 (&acc)[2]) {
  constexpr int TM = 128, TN = 64, BK = 64;
  const int lane = tid & 63;
  const int wave = tid >> 6;
  const int wrow = wave >> 1, wcol = wave & 1;

  for (int k0 = kbeg; k0 < kend; k0 += BK) {
    #pragma unroll
    for (int it = 0; it < TM / 32; ++it) {
      int c = it * 256 + tid;            // chunk index = LDS position
      int row = c >> 3, pc = c & 7;
      int gc = pc ^ (row & 7);           // which global 16B chunk lands here
      async_cp16(A + (size_t)row * K + (k0 + gc * 8),
                 &lds[(it * 256 + wave * 64) * 8]);
    }
    #pragma unroll
    for (int it = 0; it < TN / 32; ++it) {
      int c = it * 256 + tid;
      int row = c >> 3, pc = c & 7;
      int gc = pc ^ (row & 7);
      async_cp16(B + (size_t)row * K + (k0 + gc * 8),
                 &lds[TM * BK + (it * 256 + wave * 64) * 8]);
    }
    __syncthreads();

    #pragma unroll
    for (int s = 0; s < 4; ++s) {        // 4 k-steps of K=16
      const int h = s * 2 + (lane >> 5); // 16B chunk along K this lane needs
      const int rb = wcol * 32 + (lane & 31);
      bf16x8 bfr = *(const bf16x8*)&lds[TM * BK + (rb * 8 + (h ^ (rb & 7))) * 8];
      #pragma unroll
      for (int i = 0; i < 2; ++i) {
        const int ra = wrow * 64 + i * 32 + (lane & 31);
        bf16x8 afr = *(const bf16x8*)&lds[(ra * 8 + (h ^ (ra & 7))) * 8];
        acc[i] = __builtin_amdgcn_mfma_f32_32x32x16_bf16(afr, bfr, acc[i], 0, 0, 0);
      }
    }
    __syncthreads();
  }
}

// 32x32 C/D mapping (m74/m101 verified): col = lane&31,
// row = (reg&3) + 8*(reg>>2) + 4*(lane>>5), reg in [0,16).

// ---- GEMM1+GEMM2 merged: [x; proto](4608 x 1024) @ feat^T, tile 128x64 ----
// x-rows  -> Acat[row, f]=xf*relu(xf), Acat[row, 2048+f]=1-relu(xf)
// p-rows  -> Bcat[row, f]=th*c-al*(1-pres), Bcat[row, 2048+f]=-be*c
// Epilogue: LDS transpose (stride 72 u16) -> 128B-coalesced u16x8 stores.
__global__ __launch_bounds__(256) void gemm12(
    const u16* __restrict__ xb, const u16* __restrict__ pb,
    const u16* __restrict__ fb, u16* __restrict__ Acat, u16* __restrict__ Bcat,
    const float* __restrict__ alpha, const float* __restrict__ beta,
    const float* __restrict__ theta) {
  constexpr int TM = 128, TN = 64, K = 1024, N = 2048;
  constexpr int TSTRIDE = 72;            // u16; 144B rows = 9*16B aligned
  __shared__ u16 lds[(TM + TN) * 64];    // 24576 B; transpose uses 18432 B

  const int tid = threadIdx.x;
  const int lane = tid & 63;
  const int wave = tid >> 6;
  const int wrow = wave >> 1, wcol = wave & 1;
  const int bm_all = blockIdx.x * TM;
  const int bn = blockIdx.y * TN;
  const bool is_x = bm_all < 4096;       // block purely x or proto (4096%128==0)
  const u16* A = is_x ? xb + (size_t)bm_all * K : pb + (size_t)(bm_all - 4096) * K;
  const u16* B = fb + (size_t)bn * K;

  f32x16 acc[2] = {};
  mainloop(A, B, K, 0, K, tid, lds, acc);

  float th = 0.f, al = 0.f, be = 0.f;
  if (!is_x) { th = theta[0]; al = alpha[0]; be = beta[0]; }
  u16* dst = is_x ? Acat : Bcat;
  const int rowbase = is_x ? bm_all : bm_all - 4096;
  const int cl = wcol * 32 + (lane & 31);
  const int rquad = 4 * (lane >> 5);

  #pragma unroll
  for (int half = 0; half < 2; ++half) {
    __syncthreads();   // protect lds reuse (mainloop end / previous half's reads)
    #pragma unroll
    for (int i = 0; i < 2; ++i) {
      #pragma unroll
      for (int r = 0; r < 16; ++r) {
        const int rl = wrow * 64 + i * 32 + (r & 3) + 8 * (r >> 2) + rquad;
        float v = acc[i][r];
        float pres = v > 0.f ? v : 0.f;
        float o;
        if (is_x) o = half == 0 ? v * pres : 1.f - pres;
        else {
          float cc = v * pres;
          o = half == 0 ? th * cc - al * (1.f - pres) : -be * cc;
        }
        lds[rl * TSTRIDE + cl] = f2bf(o);
      }
    }
    __syncthreads();
    #pragma unroll
    for (int v = 0; v < 4; ++v) {
      const int rl = v * 32 + (tid >> 3);
      const int c8 = (tid & 7) * 8;
      u16x8 vec = *(const u16x8*)&lds[rl * TSTRIDE + c8];
      *(u16x8*)&dst[(size_t)(rowbase + rl) * (2 * N) + bn + c8 + half * N] = vec;
    }
  }
}

// ---- GEMM3 split-K: part[z] = Acat @ Bcat^T partial (bf16), tile 256x64 ----
// KSPLIT=8 (K=512/block, 8 iters), grid 16x8x8 = 1024 blocks, LDS 40KB
// -> 4 blocks/CU. Wave grid 4x1: wave = 64 rows x 64 cols, 2x2 f32x16 acc.
// 105 FLOP/staged-byte (vs 43 at 128x64). Partials bf16 thread-linear.
__global__ __launch_bounds__(256) void gemm3(
    const u16* __restrict__ Acat, const u16* __restrict__ Bcat,
    u16* __restrict__ part) {
  constexpr int TM = 256, TN = 64, K = 4096, KSPLIT = 8;
  __shared__ u16 lds[(TM + TN) * 64];    // 40960 B

  const int tid = threadIdx.x;
  const int lane = tid & 63;
  const int wave = tid >> 6;             // wave w covers rows [w*64, w*64+64)
  const int bm = blockIdx.x * TM;
  const int bn = blockIdx.y * TN;
  const int kbeg = blockIdx.z * (K / KSPLIT);
  const int kend = kbeg + (K / KSPLIT);
  const u16* A = Acat + (size_t)bm * K;
  const u16* B = Bcat + (size_t)bn * K;

  f32x16 acc[2][2] = {};
  for (int k0 = kbeg; k0 < kend; k0 += 64) {
    #pragma unroll
    for (int it = 0; it < TM / 32; ++it) {
      int c = it * 256 + tid;
      int row = c >> 3, pc = c & 7;
      int gc = pc ^ (row & 7);
      async_cp16(A + (size_t)row * K + (k0 + gc * 8),
                 &lds[(it * 256 + wave * 64) * 8]);
    }
    #pragma unroll
    for (int it = 0; it < TN / 32; ++it) {
      int c = it * 256 + tid;
      int row = c >> 3, pc = c & 7;
      int gc = pc ^ (row & 7);
      async_cp16(B + (size_t)row * K + (k0 + gc * 8),
                 &lds[TM * 64 + (it * 256 + wave * 64) * 8]);
    }
    __syncthreads();

    #pragma unroll
    for (int s = 0; s < 4; ++s) {
      const int h = s * 2 + (lane >> 5);
      bf16x8 afr[2], bfr[2];
      #pragma unroll
      for (int i = 0; i < 2; ++i) {
        const int ra = wave * 64 + i * 32 + (lane & 31);
        afr[i] = *(const bf16x8*)&lds[(ra * 8 + (h ^ (ra & 7))) * 8];
      }
      #pragma unroll
      for (int j = 0; j < 2; ++j) {
        const int rb = j * 32 + (lane & 31);
        bfr[j] = *(const bf16x8*)&lds[TM * 64 + (rb * 8 + (h ^ (rb & 7))) * 8];
      }
      #pragma unroll
      for (int i = 0; i < 2; ++i)
        #pragma unroll
        for (int j = 0; j < 2; ++j)
          acc[i][j] = __builtin_amdgcn_mfma_f32_32x32x16_bf16(afr[i], bfr[j],
                                                              acc[i][j], 0, 0, 0);
    }
    __syncthreads();
  }

  // bf16 partial dump, thread-linear: tile = 16384 u16 (32KB).
  // tileId = by*16 + bx in [0,128); chunk s = (i*2+j)*2 + h, h = reg-octet.
  const size_t pbase =
      ((size_t)blockIdx.z * 128 + blockIdx.y * 16 + blockIdx.x) * 16384;
  #pragma unroll
  for (int i = 0; i < 2; ++i)
    #pragma unroll
    for (int j = 0; j < 2; ++j)
      #pragma unroll
      for (int h = 0; h < 2; ++h) {
        u16x8 o;
        #pragma unroll
        for (int e = 0; e < 8; ++e) o[e] = f2bf(acc[i][j][h * 8 + e]);
        *(u16x8*)&part[pbase + ((i * 2 + j) * 2 + h) * 2048 + tid * 8] = o;
      }
}

// ---- reduce bf16 partials over z=0..8, scatter fp32 to out ----
// 256 blocks: 2 per tile (rb&1 selects 4 of 8 s-chunks). Mirrors gemm3 map:
// s = (i*2+j)*2+h; reg = h*8+e; row = bm + w*64 + i*32 + (reg&3)+8*(reg>>2)
// + 4*(lane>>5); col = bn + j*32 + (lane&31).
__global__ __launch_bounds__(256) void reduce8(
    const u16* __restrict__ part, float* __restrict__ out) {
  constexpr int N = 512;
  const int tid = threadIdx.x;
  const int lane = tid & 63;
  const int w = tid >> 6;
  const int tileId = blockIdx.x >> 1;
  const int s0 = (blockIdx.x & 1) * 4;
  const int bm = (tileId & 15) * 256;
  const int bn = (tileId >> 4) * 64;
  const int rquad = 4 * (lane >> 5);

  #pragma unroll
  for (int t = 0; t < 4; ++t) {
    const int s = s0 + t;
    float v[8] = {};
    #pragma unroll
    for (int z = 0; z < 8; ++z) {
      u16x8 u = *(const u16x8*)&part[((size_t)z * 128 + tileId) * 16384 +
                                     s * 2048 + tid * 8];
      #pragma unroll
      for (int e = 0; e < 8; ++e) v[e] += bf2f(u[e]);
    }
    const int i = s >> 2, j = (s >> 1) & 1, h = s & 1;
    const int gc = bn + j * 32 + (lane & 31);
    const int grb = bm + w * 64 + i * 32 + rquad;
    #pragma unroll
    for (int e = 0; e < 8; ++e) {
      const int reg = h * 8 + e;
      out[(size_t)(grb + (reg & 3) + 8 * (reg >> 2)) * N + gc] = v[e];
    }
  }
}

extern "C" void kernel_launch(void* const* d_in, const int* in_sizes, int n_in,
                              void* d_out, int out_size, void* d_ws, size_t ws_size,
                              hipStream_t stream) {
  const float* x     = (const float*)d_in[0];
  const float* feat  = (const float*)d_in[1];
  const float* proto = (const float*)d_in[2];
  const float* alpha = (const float*)d_in[3];
  const float* beta  = (const float*)d_in[4];
  const float* theta = (const float*)d_in[5];
  float* out = (float*)d_out;

  constexpr int Bb = 4096, Ii = 1024, Pp = 512, Ff = 2048;

  // ws layout: region0 [0, 33.55MB) serves cast outputs (consumed by gemm12),
  // then is reused for gemm3's bf16 partials (8 splits x 128 tiles x 32KB).
  char* ws = (char*)d_ws;
  u16* xb   = (u16*)ws;                               // 8.4 MB
  u16* fb   = xb + (size_t)Bb * Ii;                   // 4.2 MB
  u16* pb   = fb + (size_t)Ff * Ii;                   // 1.0 MB
  u16* part = (u16*)ws;                               // 33.55 MB (aliases casts)
  size_t r0 = (size_t)8 * 128 * 16384 * 2;            // 33.55 MB
  u16* Acat = (u16*)(ws + r0);                        // 33.6 MB
  u16* Bcat = Acat + (size_t)Bb * 2 * Ff;             // 4.2 MB  (total ~71.3 MB)

  const int n1 = Bb * Ii, n2 = Ff * Ii, n3 = Pp * Ii;
  cast3<<<((n1 + n2 + n3) / 8 + 255) / 256, 256, 0, stream>>>(
      x, feat, proto, xb, n1, n2, n3);

  // merged GEMM1+GEMM2: M=4608 (36 row-tiles of 128), N=2048 (32 col-tiles of 64)
  gemm12<<<dim3(36, 32), 256, 0, stream>>>(xb, pb, fb, Acat, Bcat, alpha, beta, theta);

  // GEMM3: 4096x512, K=4096 split 8 ways, 256x64 tiles -> 1024 blocks
  gemm3<<<dim3(Bb / 256, Pp / 64, 8), 256, 0, stream>>>(Acat, Bcat, part);

  // reduce z=0..8 -> out (2 blocks per tile)
  reduce8<<<256, 256, 0, stream>>>(part, out);
}

// Round 12
// 142.452 us; speedup vs baseline: 1.0473x; 1.0473x over previous
//
#include <hip/hip_runtime.h>
#include <cstdint>

typedef __attribute__((ext_vector_type(8))) short bf16x8;    // 8 bf16 = 4 VGPRs
typedef __attribute__((ext_vector_type(16))) float f32x16;   // 32x32 MFMA C/D
typedef __attribute__((ext_vector_type(4))) float f4;
typedef __attribute__((ext_vector_type(8))) unsigned short u16x8;
typedef unsigned short u16;

// JOURNAL:
// R6: __launch_bounds__(256,6) forced VGPR 72->40, scratch spills (+36MB traffic).
// R7: device-scope __threadfence() reduction inside gemm3 = L2 writeback storms.
// R8: (256,8) neutral; residency saturated ~4 blocks/CU.
// R9: 32x32x16 MFMA beats 16x16x32 (-5us). BEST = 148.4us.
// R10: 256x64/KSPLIT=8 neutral (mainloop at plateau); bf16 partials numerically
//      free (absmax unchanged 32768).
// R11: bf16 partials + 1024-block reduce CRASHED (GPU abort). part aliased the
//      cast region with an exact-boundary fit. R12: identical logic, part moved
//      to a dedicated non-aliased region (only variable changed).

__device__ __forceinline__ u16 f2bf(float f) {
  uint32_t u = __builtin_bit_cast(uint32_t, f);
  u += 0x7fffu + ((u >> 16) & 1u);          // round-to-nearest-even
  return (u16)(u >> 16);
}

__device__ __forceinline__ float bf2f(u16 h) {
  return __builtin_bit_cast(float, (uint32_t)h << 16);
}

__device__ __forceinline__ void async_cp16(const void* g, void* l) {
  __builtin_amdgcn_global_load_lds(
      (const __attribute__((address_space(1))) uint32_t*)g,
      (__attribute__((address_space(3))) uint32_t*)l, 16, 0, 0);
}

// cast x | features | prototypes -> contiguous bf16 region in ws (8 elem/thread)
__global__ __launch_bounds__(256) void cast3(
    const float* __restrict__ x, const float* __restrict__ f,
    const float* __restrict__ p, u16* __restrict__ dst,
    int n1, int n2, int n3) {
  int i = (blockIdx.x * 256 + threadIdx.x) * 8;
  const float* src;
  int local;
  if (i < n1) { src = x; local = i; }
  else if (i < n1 + n2) { src = f; local = i - n1; }
  else if (i < n1 + n2 + n3) { src = p; local = i - n1 - n2; }
  else return;
  f4 a = *(const f4*)(src + local);
  f4 b = *(const f4*)(src + local + 4);
  u16x8 o;
  o[0] = f2bf(a.x); o[1] = f2bf(a.y); o[2] = f2bf(a.z); o[3] = f2bf(a.w);
  o[4] = f2bf(b.x); o[5] = f2bf(b.y); o[6] = f2bf(b.z); o[7] = f2bf(b.w);
  *(u16x8*)(dst + i) = o;
}

// ---- shared main loop (TM=128, TN=64): C += A @ B^T with 32x32x16 MFMA ----
// A,B pre-offset to tile base row; 16B-chunk XOR swizzle (0 bank conflicts).
// Wave grid 2x2: wave covers 64 rows x 32 cols = 2 stacked 32x32 acc tiles.
__device__ __forceinline__ void mainloop(
    const u16* __restrict__ A, const u16* __restrict__ B, int K,
    int kbeg, int kend, int tid, u16* lds, f32x16 (&acc)[2]) {
  constexpr int TM = 128, TN = 64, BK = 64;
  const int lane = tid & 63;
  const int wave = tid >> 6;
  const int wrow = wave >> 1, wcol = wave & 1;

  for (int k0 = kbeg; k0 < kend; k0 += BK) {
    #pragma unroll
    for (int it = 0; it < TM / 32; ++it) {
      int c = it * 256 + tid;            // chunk index = LDS position
      int row = c >> 3, pc = c & 7;
      int gc = pc ^ (row & 7);           // which global 16B chunk lands here
      async_cp16(A + (size_t)row * K + (k0 + gc * 8),
                 &lds[(it * 256 + wave * 64) * 8]);
    }
    #pragma unroll
    for (int it = 0; it < TN / 32; ++it) {
      int c = it * 256 + tid;
      int row = c >> 3, pc = c & 7;
      int gc = pc ^ (row & 7);
      async_cp16(B + (size_t)row * K + (k0 + gc * 8),
                 &lds[TM * BK + (it * 256 + wave * 64) * 8]);
    }
    __syncthreads();

    #pragma unroll
    for (int s = 0; s < 4; ++s) {        // 4 k-steps of K=16
      const int h = s * 2 + (lane >> 5); // 16B chunk along K this lane needs
      const int rb = wcol * 32 + (lane & 31);
      bf16x8 bfr = *(const bf16x8*)&lds[TM * BK + (rb * 8 + (h ^ (rb & 7))) * 8];
      #pragma unroll
      for (int i = 0; i < 2; ++i) {
        const int ra = wrow * 64 + i * 32 + (lane & 31);
        bf16x8 afr = *(const bf16x8*)&lds[(ra * 8 + (h ^ (ra & 7))) * 8];
        acc[i] = __builtin_amdgcn_mfma_f32_32x32x16_bf16(afr, bfr, acc[i], 0, 0, 0);
      }
    }
    __syncthreads();
  }
}

// 32x32 C/D mapping (m74/m101 verified): col = lane&31,
// row = (reg&3) + 8*(reg>>2) + 4*(lane>>5), reg in [0,16).

// ---- GEMM1+GEMM2 merged: [x; proto](4608 x 1024) @ feat^T, tile 128x64 ----
// x-rows  -> Acat[row, f]=xf*relu(xf), Acat[row, 2048+f]=1-relu(xf)
// p-rows  -> Bcat[row, f]=th*c-al*(1-pres), Bcat[row, 2048+f]=-be*c
// Epilogue: LDS transpose (stride 72 u16) -> 128B-coalesced u16x8 stores.
__global__ __launch_bounds__(256) void gemm12(
    const u16* __restrict__ xb, const u16* __restrict__ pb,
    const u16* __restrict__ fb, u16* __restrict__ Acat, u16* __restrict__ Bcat,
    const float* __restrict__ alpha, const float* __restrict__ beta,
    const float* __restrict__ theta) {
  constexpr int TM = 128, TN = 64, K = 1024, N = 2048;
  constexpr int TSTRIDE = 72;            // u16; 144B rows = 9*16B aligned
  __shared__ u16 lds[(TM + TN) * 64];    // 24576 B; transpose uses 18432 B

  const int tid = threadIdx.x;
  const int lane = tid & 63;
  const int wave = tid >> 6;
  const int wrow = wave >> 1, wcol = wave & 1;
  const int bm_all = blockIdx.x * TM;
  const int bn = blockIdx.y * TN;
  const bool is_x = bm_all < 4096;       // block purely x or proto (4096%128==0)
  const u16* A = is_x ? xb + (size_t)bm_all * K : pb + (size_t)(bm_all - 4096) * K;
  const u16* B = fb + (size_t)bn * K;

  f32x16 acc[2] = {};
  mainloop(A, B, K, 0, K, tid, lds, acc);

  float th = 0.f, al = 0.f, be = 0.f;
  if (!is_x) { th = theta[0]; al = alpha[0]; be = beta[0]; }
  u16* dst = is_x ? Acat : Bcat;
  const int rowbase = is_x ? bm_all : bm_all - 4096;
  const int cl = wcol * 32 + (lane & 31);
  const int rquad = 4 * (lane >> 5);

  #pragma unroll
  for (int half = 0; half < 2; ++half) {
    __syncthreads();   // protect lds reuse (mainloop end / previous half's reads)
    #pragma unroll
    for (int i = 0; i < 2; ++i) {
      #pragma unroll
      for (int r = 0; r < 16; ++r) {
        const int rl = wrow * 64 + i * 32 + (r & 3) + 8 * (r >> 2) + rquad;
        float v = acc[i][r];
        float pres = v > 0.f ? v : 0.f;
        float o;
        if (is_x) o = half == 0 ? v * pres : 1.f - pres;
        else {
          float cc = v * pres;
          o = half == 0 ? th * cc - al * (1.f - pres) : -be * cc;
        }
        lds[rl * TSTRIDE + cl] = f2bf(o);
      }
    }
    __syncthreads();
    #pragma unroll
    for (int v = 0; v < 4; ++v) {
      const int rl = v * 32 + (tid >> 3);
      const int c8 = (tid & 7) * 8;
      u16x8 vec = *(const u16x8*)&lds[rl * TSTRIDE + c8];
      *(u16x8*)&dst[(size_t)(rowbase + rl) * (2 * N) + bn + c8 + half * N] = vec;
    }
  }
}

// ---- GEMM3 split-K: part[z] = Acat @ Bcat^T partial (bf16), tile 128x64 ----
// KSPLIT=4, grid 32x8x4 = 1024 blocks. Partials bf16 thread-linear:
// tile = 8192 u16; chunk s = i*2 + h (h = reg-octet), 2048 u16 each.
__global__ __launch_bounds__(256) void gemm3(
    const u16* __restrict__ Acat, const u16* __restrict__ Bcat,
    u16* __restrict__ part) {
  constexpr int TM = 128, TN = 64, K = 4096, KSPLIT = 4;
  __shared__ u16 lds[(TM + TN) * 64];    // 24576 B

  const int tid = threadIdx.x;
  const int bm = blockIdx.x * TM;
  const int bn = blockIdx.y * TN;
  const int kbeg = blockIdx.z * (K / KSPLIT);
  const int kend = kbeg + (K / KSPLIT);

  f32x16 acc[2] = {};
  mainloop(Acat + (size_t)bm * K, Bcat + (size_t)bn * K, K, kbeg, kend,
           tid, lds, acc);

  const size_t pbase =
      ((size_t)blockIdx.z * 256 + blockIdx.y * 32 + blockIdx.x) * 8192;
  #pragma unroll
  for (int i = 0; i < 2; ++i)
    #pragma unroll
    for (int h = 0; h < 2; ++h) {
      u16x8 o;
      #pragma unroll
      for (int e = 0; e < 8; ++e) o[e] = f2bf(acc[i][h * 8 + e]);
      *(u16x8*)&part[pbase + (i * 2 + h) * 2048 + tid * 8] = o;
    }
}

// ---- reduce bf16 partials over z=0..4, scatter fp32 to out ----
// 1024 blocks: one s-chunk per block (tileId = bx>>2, s = bx&3). Mirrors
// gemm3 map: s = i*2+h; reg = h*8+e; row = bm + wrow*64 + i*32 +
// (reg&3)+8*(reg>>2)+4*(lane>>5); col = bn + wcol*32 + (lane&31).
__global__ __launch_bounds__(256) void reduce4(
    const u16* __restrict__ part, float* __restrict__ out) {
  constexpr int N = 512;
  const int tid = threadIdx.x;
  const int lane = tid & 63;
  const int wave = tid >> 6;
  const int wrow = wave >> 1, wcol = wave & 1;
  const int tileId = blockIdx.x >> 2;      // 0..255 = by*32+bx
  const int s = blockIdx.x & 3;
  const int bm = (tileId & 31) * 128;
  const int bn = (tileId >> 5) * 64;

  float v[8] = {};
  #pragma unroll
  for (int z = 0; z < 4; ++z) {
    u16x8 u = *(const u16x8*)&part[((size_t)z * 256 + tileId) * 8192 +
                                   s * 2048 + tid * 8];
    #pragma unroll
    for (int e = 0; e < 8; ++e) v[e] += bf2f(u[e]);
  }
  const int i = s >> 1, h = s & 1;
  const int gc = bn + wcol * 32 + (lane & 31);
  const int grb = bm + wrow * 64 + i * 32 + 4 * (lane >> 5);
  #pragma unroll
  for (int e = 0; e < 8; ++e) {
    const int reg = h * 8 + e;
    out[(size_t)(grb + (reg & 3) + 8 * (reg >> 2)) * N + gc] = v[e];
  }
}

extern "C" void kernel_launch(void* const* d_in, const int* in_sizes, int n_in,
                              void* d_out, int out_size, void* d_ws, size_t ws_size,
                              hipStream_t stream) {
  const float* x     = (const float*)d_in[0];
  const float* feat  = (const float*)d_in[1];
  const float* proto = (const float*)d_in[2];
  const float* alpha = (const float*)d_in[3];
  const float* beta  = (const float*)d_in[4];
  const float* theta = (const float*)d_in[5];
  float* out = (float*)d_out;

  constexpr int Bb = 4096, Ii = 1024, Pp = 512, Ff = 2048;

  // ws layout (NO aliasing — R12 defensive change): casts | Acat | Bcat | part.
  // Total ~88 MB of the 256 MiB workspace.
  char* ws = (char*)d_ws;
  u16* xb   = (u16*)ws;                               // 8.4 MB
  u16* fb   = xb + (size_t)Bb * Ii;                   // 4.2 MB
  u16* pb   = fb + (size_t)Ff * Ii;                   // 1.0 MB
  size_t r0 = 33554432;                               // 32 MiB region0 (casts)
  u16* Acat = (u16*)(ws + r0);                        // 33.6 MB
  u16* Bcat = Acat + (size_t)Bb * 2 * Ff;             // 4.2 MB
  u16* part = Bcat + (size_t)Pp * 2 * Ff;             // 16.8 MB (dedicated)

  const int n1 = Bb * Ii, n2 = Ff * Ii, n3 = Pp * Ii;
  cast3<<<((n1 + n2 + n3) / 8 + 255) / 256, 256, 0, stream>>>(
      x, feat, proto, xb, n1, n2, n3);

  // merged GEMM1+GEMM2: M=4608 (36 row-tiles of 128), N=2048 (32 col-tiles of 64)
  gemm12<<<dim3(36, 32), 256, 0, stream>>>(xb, pb, fb, Acat, Bcat, alpha, beta, theta);

  // GEMM3: 4096x512, K=4096 split 4 ways -> 1024 blocks, bf16 partials
  gemm3<<<dim3(Bb / 128, Pp / 64, 4), 256, 0, stream>>>(Acat, Bcat, part);

  // reduce z=0..4 -> out (4 blocks per tile, one s-chunk each)
  reduce4<<<1024, 256, 0, stream>>>(part, out);
}